// Round 7
// baseline (221.721 us; speedup 1.0000x reference)
//
#include <hip/hip_runtime.h>

#define B_DIM 32
#define T_DIM 4096
#define D_DIM 512
#define E_DIM 512
#define EPS_K 1e-7f
#define NGRP 128   // score blocks per batch, 32 t each

// ---------------------------------------------------------------------------
// K1: yp[b,d] = dot(W[d,:], y[b,:])  (yp = y @ W^T), one wave per (b,d).
// Also zeroes the 32 per-batch arrival counters used by K2 (this kernel runs
// first on the stream every launch, so counters are 0 regardless of the ws
// poison -- no persistent state).
// ---------------------------------------------------------------------------
__global__ __launch_bounds__(256) void yp_kernel(const float* __restrict__ y,
                                                 const float* __restrict__ W,
                                                 float* __restrict__ yp,
                                                 int* __restrict__ cnt) {
    if (blockIdx.x == 0 && blockIdx.y == 0 && threadIdx.x < B_DIM)
        cnt[threadIdx.x] = 0;

    const int b    = blockIdx.y;
    const int wave = threadIdx.x >> 6;
    const int lane = threadIdx.x & 63;
    const int d    = blockIdx.x * 4 + wave;

    const float4* Wv = (const float4*)(W + (size_t)d * E_DIM);
    const float4* yv = (const float4*)(y + (size_t)b * E_DIM);
    const float4 w0 = Wv[lane];
    const float4 w1 = Wv[lane + 64];
    const float4 y0 = yv[lane];
    const float4 y1 = yv[lane + 64];

    float p = w0.x*y0.x + w0.y*y0.y + w0.z*y0.z + w0.w*y0.w
            + w1.x*y1.x + w1.y*y1.y + w1.z*y1.z + w1.w*y1.w;
#pragma unroll
    for (int off = 32; off > 0; off >>= 1) p += __shfl_xor(p, off);

    if (lane == 0) yp[(size_t)b * D_DIM + d] = p;
}

// ---------------------------------------------------------------------------
// K2: scores + per-block partial + last-block-per-batch normalize (stream-K
// style fixup; no separate norm kernel, no grid sync).
// grid (NGRP, B), 256 thr = 4 waves; each wave handles 8 consecutive t.
// Deterministic: the partial reduce is a fixed-index tree over partials[],
// identical arithmetic no matter which block arrives last.
// ---------------------------------------------------------------------------
__global__ __launch_bounds__(256) void score_kernel(const float* __restrict__ x,
                                                    const float* __restrict__ yp,
                                                    const float* __restrict__ bias,
                                                    const int* __restrict__ mask,
                                                    float* __restrict__ a_raw,
                                                    float* __restrict__ partials,
                                                    int* __restrict__ cnt,
                                                    float* __restrict__ out) {
    const int g    = blockIdx.x;
    const int b    = blockIdx.y;
    const int wave = threadIdx.x >> 6;
    const int lane = threadIdx.x & 63;
    const int t0   = g * 32 + wave * 8;

    const float4* ypv = (const float4*)(yp + (size_t)b * D_DIM);
    const float4 w0 = ypv[lane];
    const float4 w1 = ypv[lane + 64];

    const float4* xv = (const float4*)(x + ((size_t)b * T_DIM + (size_t)t0) * D_DIM);

    // Issue all 16 streaming loads first (64 VGPRs of x in flight).
    float4 xa[8], xb[8];
#pragma unroll
    for (int i = 0; i < 8; ++i) {
        xa[i] = xv[i * (D_DIM / 4) + lane];
        xb[i] = xv[i * (D_DIM / 4) + lane + 64];
    }

    float p[8];
#pragma unroll
    for (int i = 0; i < 8; ++i) {
        p[i] = xa[i].x*w0.x + xa[i].y*w0.y + xa[i].z*w0.z + xa[i].w*w0.w
             + xb[i].x*w1.x + xb[i].y*w1.y + xb[i].z*w1.z + xb[i].w*w1.w;
    }

    // 8 independent butterfly reduces, interleaved per step for ILP.
#pragma unroll
    for (int off = 32; off > 0; off >>= 1) {
#pragma unroll
        for (int i = 0; i < 8; ++i) p[i] += __shfl_xor(p[i], off);
    }

    // Lanes 0..7 finalize row t0+lane (coalesced 32B store).
    float a = 0.f;
    if (lane < 8) {
        float s = (lane==0)?p[0]:(lane==1)?p[1]:(lane==2)?p[2]:(lane==3)?p[3]
                :(lane==4)?p[4]:(lane==5)?p[5]:(lane==6)?p[6]:p[7];
        const int t = t0 + lane;
        const float e = expf(tanhf(s + bias[0]));
        a = mask[(size_t)b * T_DIM + t] ? e : 0.f;
        a_raw[(size_t)b * T_DIM + t] = a;
    }

    // Block partial: butterfly (lanes >=8 hold 0) + fixed 4-way LDS tree.
    float ws = a;
#pragma unroll
    for (int off = 32; off > 0; off >>= 1) ws += __shfl_xor(ws, off);

    __shared__ float ls[4];
    __shared__ float inv_s;
    __shared__ int   is_last;
    if (lane == 0) ls[wave] = ws;
    __syncthreads();
    if (threadIdx.x == 0) {
        partials[(size_t)b * NGRP + g] = (ls[0] + ls[1]) + (ls[2] + ls[3]);
        __threadfence();                       // release: a_raw + partial visible
        const int old = atomicAdd(&cnt[b], 1); // device-scope
        is_last = (old == NGRP - 1) ? 1 : 0;
    }
    __syncthreads();
    if (!is_last) return;

    // ---- Last block of batch b: reduce partials (fixed tree), normalize ----
    __threadfence();  // acquire: see all blocks' a_raw/partials
    if (threadIdx.x < 64) {
        const float* pp = partials + (size_t)b * NGRP;
        float s = pp[threadIdx.x] + pp[threadIdx.x + 64];
#pragma unroll
        for (int off = 32; off > 0; off >>= 1) s += __shfl_xor(s, off);
        if (threadIdx.x == 0) inv_s = 1.0f / (s + EPS_K);
    }
    __syncthreads();
    const float inv = inv_s;

    const float4* av = (const float4*)(a_raw + (size_t)b * T_DIM);
    float4*       ov = (float4*)(out + (size_t)b * T_DIM);
#pragma unroll
    for (int k = 0; k < 4; ++k) {
        const int idx = k * 256 + threadIdx.x;   // 1024 float4 per batch row
        const float4 v = av[idx];
        ov[idx] = make_float4(v.x * inv, v.y * inv, v.z * inv, v.w * inv);
    }
}

// ---------------------------------------------------------------------------
extern "C" void kernel_launch(void* const* d_in, const int* in_sizes, int n_in,
                              void* d_out, int out_size, void* d_ws, size_t ws_size,
                              hipStream_t stream) {
    const float* x    = (const float*)d_in[0];  // [B,T,D]
    const float* y    = (const float*)d_in[1];  // [B,E]
    const float* W    = (const float*)d_in[2];  // [D,E]
    const float* bias = (const float*)d_in[3];  // [1]
    const int*   mask = (const int*)d_in[4];    // [B,T] (bool -> int32)
    float* out = (float*)d_out;                 // [B,T]

    float* yp       = (float*)d_ws;             // B*D floats    = 64 KB
    float* a_raw    = yp + B_DIM * D_DIM;       // B*T floats    = 512 KB
    float* partials = a_raw + B_DIM * T_DIM;    // B*NGRP floats = 16 KB
    int*   cnt      = (int*)(partials + B_DIM * NGRP);  // 32 ints

    yp_kernel<<<dim3(D_DIM / 4, B_DIM), 256, 0, stream>>>(y, W, yp, cnt);
    score_kernel<<<dim3(NGRP, B_DIM), 256, 0, stream>>>(x, yp, bias, mask,
                                                        a_raw, partials, cnt, out);
}

// Round 8
// 50.702 us; speedup vs baseline: 4.3730x; 4.3730x over previous
//
#include <hip/hip_runtime.h>

#define B_DIM 32
#define T_DIM 4096
#define D_DIM 512
#define E_DIM 512
#define EPS_K 1e-7f

// ---------------------------------------------------------------------------
// K1: yp[b,d] = dot(W[d,:], y[b,:])  (yp = y @ W^T), one wave per (b,d).
// Coalesced float4 loads, 6-step butterfly. (proven R2 version)
// ---------------------------------------------------------------------------
__global__ __launch_bounds__(256) void yp_kernel(const float* __restrict__ y,
                                                 const float* __restrict__ W,
                                                 float* __restrict__ yp) {
    const int b    = blockIdx.y;
    const int wave = threadIdx.x >> 6;
    const int lane = threadIdx.x & 63;
    const int d    = blockIdx.x * 4 + wave;

    const float4* Wv = (const float4*)(W + (size_t)d * E_DIM);
    const float4* yv = (const float4*)(y + (size_t)b * E_DIM);
    const float4 w0 = Wv[lane];
    const float4 w1 = Wv[lane + 64];
    const float4 y0 = yv[lane];
    const float4 y1 = yv[lane + 64];

    float p = w0.x*y0.x + w0.y*y0.y + w0.z*y0.z + w0.w*y0.w
            + w1.x*y1.x + w1.y*y1.y + w1.z*y1.z + w1.w*y1.w;
#pragma unroll
    for (int off = 32; off > 0; off >>= 1) p += __shfl_xor(p, off);

    if (lane == 0) yp[(size_t)b * D_DIM + d] = p;
}

// ---------------------------------------------------------------------------
// K2: a_raw[b,t] = exp(tanh(dot(x[b,t,:], yp[b,:]) + bias)) * mask[b,t]
// EXACT R2 structure (single-purpose streaming kernel — no tails, no atomics;
// R5/R6/R7 showed any appended phase collapses VGPR allocation to 32-64 and
// serializes the load batch). Only change vs R2: mask is prefetched at the
// top so its latency hides under the streaming loads.
// ---------------------------------------------------------------------------
__global__ __launch_bounds__(256) void score_kernel(const float* __restrict__ x,
                                                    const float* __restrict__ yp,
                                                    const float* __restrict__ bias,
                                                    const int* __restrict__ mask,
                                                    float* __restrict__ a_raw) {
    const int b    = blockIdx.y;
    const int wave = threadIdx.x >> 6;
    const int lane = threadIdx.x & 63;
    const int t0   = blockIdx.x * 32 + wave * 8;

    // Prefetch: independent early loads (mask for this wave's 8 rows, yp).
    const int mi = mask[(size_t)b * T_DIM + t0 + (lane & 7)];

    const float4* ypv = (const float4*)(yp + (size_t)b * D_DIM);
    const float4 w0 = ypv[lane];
    const float4 w1 = ypv[lane + 64];

    const float4* xv = (const float4*)(x + ((size_t)b * T_DIM + (size_t)t0) * D_DIM);

    // Issue all 16 streaming loads first (64 VGPRs of x in flight).
    float4 xa[8], xb[8];
#pragma unroll
    for (int i = 0; i < 8; ++i) {
        xa[i] = xv[i * (D_DIM / 4) + lane];
        xb[i] = xv[i * (D_DIM / 4) + lane + 64];
    }

    float p[8];
#pragma unroll
    for (int i = 0; i < 8; ++i) {
        p[i] = xa[i].x*w0.x + xa[i].y*w0.y + xa[i].z*w0.z + xa[i].w*w0.w
             + xb[i].x*w1.x + xb[i].y*w1.y + xb[i].z*w1.z + xb[i].w*w1.w;
    }

    // 8 independent butterfly reduces, interleaved per step for ILP.
#pragma unroll
    for (int off = 32; off > 0; off >>= 1) {
#pragma unroll
        for (int i = 0; i < 8; ++i) p[i] += __shfl_xor(p[i], off);
    }

    // Lanes 0..7 finalize row t0+lane (coalesced 32B store).
    if (lane < 8) {
        float s = (lane==0)?p[0]:(lane==1)?p[1]:(lane==2)?p[2]:(lane==3)?p[3]
                :(lane==4)?p[4]:(lane==5)?p[5]:(lane==6)?p[6]:p[7];
        const int t = t0 + lane;
        const float e = expf(tanhf(s + bias[0]));
        a_raw[(size_t)b * T_DIM + t] = mi ? e : 0.f;
    }
}

// ---------------------------------------------------------------------------
// K3: out[b,t] = a_raw[b,t] / (sum_t a_raw[b,:] + EPS)
// grid (4, B), 256 thr. Each batch's 4 blocks REDUNDANTLY compute the batch
// sum with an identical fixed-index tree (bitwise-identical inv_s across
// blocks -> deterministic), then each block writes its quarter of the row.
// 128 blocks (vs R2's 32) for latency hiding; no score-side partials needed.
// ---------------------------------------------------------------------------
__global__ __launch_bounds__(256) void norm_kernel(const float* __restrict__ a_raw,
                                                   float* __restrict__ out) {
    const int b   = blockIdx.y;
    const int bx  = blockIdx.x;      // quarter 0..3
    const int tid = threadIdx.x;

    const float4* av = (const float4*)(a_raw + (size_t)b * T_DIM);

    // Every block reads the full row with the same index pattern.
    float4 v0 = av[tid];
    float4 v1 = av[tid + 256];
    float4 v2 = av[tid + 512];
    float4 v3 = av[tid + 768];

    float s = ((v0.x + v0.y) + (v0.z + v0.w)) + ((v1.x + v1.y) + (v1.z + v1.w))
            + ((v2.x + v2.y) + (v2.z + v2.w)) + ((v3.x + v3.y) + (v3.z + v3.w));
#pragma unroll
    for (int off = 32; off > 0; off >>= 1) s += __shfl_xor(s, off);

    __shared__ float wsum[4];
    __shared__ float inv_s;
    const int wave = tid >> 6;
    const int lane = tid & 63;
    if (lane == 0) wsum[wave] = s;
    __syncthreads();
    if (tid == 0)
        inv_s = 1.0f / (((wsum[0] + wsum[1]) + (wsum[2] + wsum[3])) + EPS_K);
    __syncthreads();
    const float inv = inv_s;

    // Write this block's quarter (value already held in registers).
    const float4 v = (bx == 0) ? v0 : (bx == 1) ? v1 : (bx == 2) ? v2 : v3;
    ((float4*)(out + (size_t)b * T_DIM))[bx * 256 + tid] =
        make_float4(v.x * inv, v.y * inv, v.z * inv, v.w * inv);
}

// ---------------------------------------------------------------------------
extern "C" void kernel_launch(void* const* d_in, const int* in_sizes, int n_in,
                              void* d_out, int out_size, void* d_ws, size_t ws_size,
                              hipStream_t stream) {
    const float* x    = (const float*)d_in[0];  // [B,T,D]
    const float* y    = (const float*)d_in[1];  // [B,E]
    const float* W    = (const float*)d_in[2];  // [D,E]
    const float* bias = (const float*)d_in[3];  // [1]
    const int*   mask = (const int*)d_in[4];    // [B,T] (bool -> int32)
    float* out = (float*)d_out;                 // [B,T]

    float* yp    = (float*)d_ws;                // B*D floats = 64 KB
    float* a_raw = yp + B_DIM * D_DIM;          // B*T floats = 512 KB

    yp_kernel<<<dim3(D_DIM / 4, B_DIM), 256, 0, stream>>>(y, W, yp);
    score_kernel<<<dim3(T_DIM / 32, B_DIM), 256, 0, stream>>>(x, yp, bias, mask, a_raw);
    norm_kernel<<<dim3(4, B_DIM), 256, 0, stream>>>(a_raw, out);
}